// Round 2
// baseline (1459.352 us; speedup 1.0000x reference)
//
#include <hip/hip_runtime.h>
#include <hip/hip_bf16.h>

#define DEVI __device__ __forceinline__

typedef short bf16x8 __attribute__((ext_vector_type(8)));
typedef float f32x4 __attribute__((ext_vector_type(4)));

#define NBLK 256

// ---- helpers -------------------------------------------------------------

DEVI unsigned short f2b(float f) {  // f32 -> bf16 bits, RNE
    union { float f; unsigned u; } x; x.f = f;
    unsigned r = x.u + 0x7fffu + ((x.u >> 16) & 1u);
    return (unsigned short)(r >> 16);
}

DEVI float b2f(unsigned short u) {
    union { unsigned u; float f; } x; x.u = ((unsigned)u) << 16; return x.f;
}

DEVI void gld_lds16(const void* g, void* l) {
    __builtin_amdgcn_global_load_lds(
        (const __attribute__((address_space(1))) void*)g,
        (__attribute__((address_space(3))) void*)l, 16, 0, 0);
}

// ---- f32 -> bf16 convert (vectorized, grid-stride) -----------------------

__global__ __launch_bounds__(256) void cvt_f32_bf16(
    const float* __restrict__ src, unsigned short* __restrict__ dst, int n4)
{
    int stride = gridDim.x * 256;
    for (int i = blockIdx.x * 256 + threadIdx.x; i < n4; i += stride) {
        float4 v = reinterpret_cast<const float4*>(src)[i];
        ushort4 o;
        o.x = f2b(v.x); o.y = f2b(v.y); o.z = f2b(v.z); o.w = f2b(v.w);
        reinterpret_cast<ushort4*>(dst)[i] = o;
    }
}

// ---- GEMM: C[M,N] = A[M,K] @ B[N,K]^T + bias[N] (+resid) -----------------
// tile 128x128, BK=32, 4 waves, double-buffered global_load_lds staging.
// EPI: 0 = f32 out, 2 = bf16 out + f32 residual, 3 = bf16 out remapped
//      row (b*36+t) -> (t*256+b)   [for step-contiguous gi]

template<int EPI>
__global__ __launch_bounds__(256) void gemm_bt(
    const unsigned short* __restrict__ A, const unsigned short* __restrict__ Bm,
    const float* __restrict__ bias, const float* resid,
    float* outF, unsigned short* outB,
    int Mn, int Nn, int K, int mtiles)
{
    __shared__ short lds[2][2][128 * 32];
    const int tid = threadIdx.x;
    const int lane = tid & 63, w = tid >> 6;
    const int bid = blockIdx.x;
    const int mt = bid % mtiles, nt = bid / mtiles;
    const int m0 = mt * 128, n0 = nt * 128;
    const int fr = lane & 15, kg = lane >> 4;
    const int wr = (w >> 1) * 64, wc = (w & 1) * 64;

    auto stage = [&](int buf, int k0) {
#pragma unroll
        for (int rnd = 0; rnd < 2; ++rnd) {
            int chunk = rnd * 256 + w * 64;      // wave-uniform
            int slot = chunk + lane;
            int row = slot >> 2, ks = slot & 3;
            gld_lds16(A + (size_t)(m0 + row) * K + k0 + ks * 8,
                      (void*)&lds[buf][0][chunk * 8]);
        }
#pragma unroll
        for (int rnd = 0; rnd < 2; ++rnd) {
            int chunk = rnd * 256 + w * 64;
            int slot = chunk + lane;
            int row = slot >> 2, ks = slot & 3;
            gld_lds16(Bm + (size_t)(n0 + row) * K + k0 + ks * 8,
                      (void*)&lds[buf][1][chunk * 8]);
        }
    };

    f32x4 acc[4][4] = {};

    stage(0, 0);
    __syncthreads();
    const int nk = K >> 5;
    for (int kt = 0; kt < nk; ++kt) {
        int buf = kt & 1;
        if (kt + 1 < nk) stage(buf ^ 1, (kt + 1) * 32);
        const short* As = lds[buf][0];
        const short* Bs = lds[buf][1];
        bf16x8 af[4], bfv[4];
#pragma unroll
        for (int m = 0; m < 4; ++m)
            af[m] = *(const bf16x8*)&As[(wr + m * 16 + fr) * 32 + kg * 8];
#pragma unroll
        for (int n = 0; n < 4; ++n)
            bfv[n] = *(const bf16x8*)&Bs[(wc + n * 16 + fr) * 32 + kg * 8];
#pragma unroll
        for (int m = 0; m < 4; ++m)
#pragma unroll
            for (int n = 0; n < 4; ++n)
                acc[m][n] = __builtin_amdgcn_mfma_f32_16x16x32_bf16(
                    af[m], bfv[n], acc[m][n], 0, 0, 0);
        __syncthreads();
    }

    // epilogue: D[row][col], col = lane&15, row = (lane>>4)*4 + reg
#pragma unroll
    for (int n = 0; n < 4; ++n) {
        int col = n0 + wc + n * 16 + fr;
        float bc = bias[col];
#pragma unroll
        for (int m = 0; m < 4; ++m) {
            f32x4 v = acc[m][n];
#pragma unroll
            for (int i = 0; i < 4; ++i) {
                int row = m0 + wr + m * 16 + kg * 4 + i;
                float val = v[i] + bc;
                if (EPI == 0) {
                    outF[(size_t)row * Nn + col] = val;
                } else if (EPI == 2) {
                    size_t idx = (size_t)row * Nn + col;
                    val += resid[idx];
                    outB[idx] = f2b(val);
                } else {  // EPI == 3: remap (b*36+t) -> (t*256+b)
                    int b = row / 36, t = row - b * 36;
                    outB[(size_t)(t * 256 + b) * Nn + col] = f2b(val);
                }
            }
        }
    }
}

// ---- l2norm over last dim (1024) + broadcast-add oimages -----------------

__global__ __launch_bounds__(256) void l2norm_add(
    const float* fin, const float* __restrict__ oimg,
    float* foutF, unsigned short* __restrict__ foutB)
{
    int row = blockIdx.x;          // 0..9215  (b*36+n)
    int b = row / 36;
    float4 v = reinterpret_cast<const float4*>(fin + (size_t)row * 1024)[threadIdx.x];
    float s = v.x * v.x + v.y * v.y + v.z * v.z + v.w * v.w;
#pragma unroll
    for (int o = 32; o; o >>= 1) s += __shfl_down(s, o, 64);
    __shared__ float ws4[4];
    int lane = threadIdx.x & 63, w = threadIdx.x >> 6;
    if (lane == 0) ws4[w] = s;
    __syncthreads();
    float tot = ws4[0] + ws4[1] + ws4[2] + ws4[3];
    float inv = 1.0f / (sqrtf(tot) + 1e-8f);
    float4 o4 = reinterpret_cast<const float4*>(oimg + (size_t)b * 1024)[threadIdx.x];
    float4 y;
    y.x = v.x * inv + o4.x; y.y = v.y * inv + o4.y;
    y.z = v.z * inv + o4.z; y.w = v.w * inv + o4.w;
    reinterpret_cast<float4*>(foutF + (size_t)row * 1024)[threadIdx.x] = y;
    ushort4 yb; yb.x = f2b(y.x); yb.y = f2b(y.y); yb.z = f2b(y.z); yb.w = f2b(y.w);
    reinterpret_cast<ushort4*>(foutB + (size_t)row * 1024)[threadIdx.x] = yb;
}

// ---- fast two-phase grid barrier (cooperative launch required) -----------
// bar[b*16] : per-block arrive flags (64B apart); bar[NBLK*16] : release.

DEVI void pgrid_sync(unsigned* bar, unsigned gen) {
    __syncthreads();
    if (blockIdx.x == 0) {
        int b = threadIdx.x;
        if (b > 0) {
            int guard = 0;
            while (__hip_atomic_load(&bar[b * 16], __ATOMIC_ACQUIRE,
                                     __HIP_MEMORY_SCOPE_AGENT) < gen) {
                __builtin_amdgcn_s_sleep(1);
                if (++guard > (1 << 22)) break;
            }
        }
        __syncthreads();
        if (threadIdx.x == 0)
            __hip_atomic_store(&bar[NBLK * 16], gen, __ATOMIC_RELEASE,
                               __HIP_MEMORY_SCOPE_AGENT);
    } else {
        if (threadIdx.x == 0) {
            __hip_atomic_store(&bar[blockIdx.x * 16], gen, __ATOMIC_RELEASE,
                               __HIP_MEMORY_SCOPE_AGENT);
            int guard = 0;
            while (__hip_atomic_load(&bar[NBLK * 16], __ATOMIC_ACQUIRE,
                                     __HIP_MEMORY_SCOPE_AGENT) < gen) {
                __builtin_amdgcn_s_sleep(1);
                if (++guard > (1 << 22)) break;
            }
        }
        __syncthreads();
    }
}

// ---- persistent GRU: all 36 steps in one cooperative kernel ---------------
// 256 WGs = 4 batch-tiles(64) x 64 col-tiles(16). whh slice (48x1024 bf16,
// 96 KB) lives in LDS for the whole kernel (XOR-swizzled chunks). h f32 state
// lives in registers (4 cells/thread); bf16 shadow ping-pongs via global.

__global__ __launch_bounds__(256, 1) void gru_persist(
    const unsigned short* __restrict__ whhB,   // (3072,1024) bf16
    const unsigned short* __restrict__ giB,    // (36*256, 3072) bf16, t-major
    const float* __restrict__ bhh,
    unsigned short* __restrict__ hA,           // ping (256,1024) bf16
    unsigned short* __restrict__ hBb,          // pong
    float* __restrict__ hfin,                  // (256,1024) f32 final
    unsigned* __restrict__ bar)
{
    __shared__ short whs[48 * 1024];           // 96 KB
    const int tid = threadIdx.x, lane = tid & 63, w = tid >> 6;
    const int wg = blockIdx.x;
    const int b0 = (wg & 3) * 64;
    const int e0 = (wg >> 2) * 16;
    const int fr = lane & 15, kg = lane >> 4;
    const int sz = fr & 7;                     // row-XOR swizzle key

    // one-time whh slice load: 48 rows x 128 16B-chunks, pre-swizzled source
    for (int it = 0; it < 24; ++it) {
        int slot = it * 256 + tid;             // dest = base + lane*16  ✓
        int j = slot >> 7, pc = slot & 127;
        int gc = pc ^ (j & 7);
        int grow = (j >> 4) * 1024 + e0 + (j & 15);
        gld_lds16(whhB + (size_t)grow * 1024 + gc * 8, (void*)&whs[slot * 8]);
    }
    __syncthreads();

    const int e = e0 + fr;
    const float bhr = bhh[e], bhz = bhh[1024 + e], bhn = bhh[2048 + e];
    float hreg[4] = {0.f, 0.f, 0.f, 0.f};
    int bb[4];
#pragma unroll
    for (int i = 0; i < 4; ++i) bb[i] = b0 + w * 16 + kg * 4 + i;
    const int arow = b0 + w * 16 + fr;         // this lane's A-row (batch)

    unsigned short* hbuf[2] = { hA, hBb };

    for (int t = 0; t < 36; ++t) {
        const unsigned short* hc = hbuf[t & 1];
        unsigned short* hn = hbuf[(t + 1) & 1];

        // gi for this step (t-major layout: contiguous 1.5MB slab per step)
        const unsigned short* gbase = giB + (size_t)t * 256 * 3072 + e;
        unsigned short giu[4][3];
#pragma unroll
        for (int i = 0; i < 4; ++i) {
            const unsigned short* g = gbase + (size_t)bb[i] * 3072;
            giu[i][0] = g[0]; giu[i][1] = g[1024]; giu[i][2] = g[2048];
        }

        // all 32 A-fragments straight to VGPRs (deep prefetch, no LDS)
        const unsigned short* hrow = hc + (size_t)arow * 1024 + kg * 8;
        bf16x8 av[32];
#pragma unroll
        for (int kt = 0; kt < 32; ++kt)
            av[kt] = *(const bf16x8*)(hrow + kt * 32);

        f32x4 a0 = {}, a1 = {}, a2 = {};
#pragma unroll
        for (int kt = 0; kt < 32; ++kt) {
            const int c0 = kt * 4 + kg;
            bf16x8 w0 = *(const bf16x8*)&whs[(0 * 16 + fr) * 1024 + ((c0 ^ sz) << 3)];
            a0 = __builtin_amdgcn_mfma_f32_16x16x32_bf16(av[kt], w0, a0, 0, 0, 0);
            bf16x8 w1 = *(const bf16x8*)&whs[(1 * 16 + fr) * 1024 + ((c0 ^ sz) << 3)];
            a1 = __builtin_amdgcn_mfma_f32_16x16x32_bf16(av[kt], w1, a1, 0, 0, 0);
            bf16x8 w2 = *(const bf16x8*)&whs[(2 * 16 + fr) * 1024 + ((c0 ^ sz) << 3)];
            a2 = __builtin_amdgcn_mfma_f32_16x16x32_bf16(av[kt], w2, a2, 0, 0, 0);
        }

        // gate math; h state stays in f32 registers
#pragma unroll
        for (int i = 0; i < 4; ++i) {
            float ir = b2f(giu[i][0]), iz = b2f(giu[i][1]), inn = b2f(giu[i][2]);
            float r = 1.f / (1.f + __expf(-(ir + a0[i] + bhr)));
            float z = 1.f / (1.f + __expf(-(iz + a1[i] + bhz)));
            float n = tanhf(inn + r * (a2[i] + bhn));
            hreg[i] = (1.f - z) * n + z * hreg[i];
        }

        if (t == 35) {
#pragma unroll
            for (int i = 0; i < 4; ++i)
                hfin[(size_t)bb[i] * 1024 + e] = hreg[i];
        } else {
#pragma unroll
            for (int i = 0; i < 4; ++i)
                hn[(size_t)bb[i] * 1024 + e] = f2b(hreg[i]);
            pgrid_sync(bar, (unsigned)(t + 1));
        }
    }
}

__global__ __launch_bounds__(256) void zero_state(
    unsigned short* hb0, unsigned* bar)
{
    int i = blockIdx.x * 256 + threadIdx.x;    // grid 1024 -> 262144
    if (i < 256 * 1024) hb0[i] = 0;
    if (i < 8192) bar[i] = 0;
}

__global__ __launch_bounds__(256) void final_norm(
    const float* __restrict__ hf, float* __restrict__ out)
{
    int row = blockIdx.x;   // 0..255
    float4 v = reinterpret_cast<const float4*>(hf + (size_t)row * 1024)[threadIdx.x];
    float s = v.x * v.x + v.y * v.y + v.z * v.z + v.w * v.w;
#pragma unroll
    for (int o = 32; o; o >>= 1) s += __shfl_down(s, o, 64);
    __shared__ float ws4[4];
    int lane = threadIdx.x & 63, w = threadIdx.x >> 6;
    if (lane == 0) ws4[w] = s;
    __syncthreads();
    float tot = ws4[0] + ws4[1] + ws4[2] + ws4[3];
    float inv = 1.0f / (sqrtf(tot) + 1e-8f);
    float4 y; y.x = v.x * inv; y.y = v.y * inv; y.z = v.z * inv; y.w = v.w * inv;
    reinterpret_cast<float4*>(out + (size_t)row * 1024)[threadIdx.x] = y;
}

// ---- launch ---------------------------------------------------------------

extern "C" void kernel_launch(void* const* d_in, const int* in_sizes, int n_in,
                              void* d_out, int out_size, void* d_ws, size_t ws_size,
                              hipStream_t stream)
{
    constexpr int cB = 256, cN = 36, cIMG = 2048, cE = 1024, cH3 = 3072;
    constexpr int cM = cB * cN;  // 9216

    const float* images  = (const float*)d_in[0];
    const float* oimages = (const float*)d_in[1];
    const float* wl_w    = (const float*)d_in[2];
    const float* wl_b    = (const float*)d_in[3];
    // d_in[4..7]: wk_w, wk_b, wq_w, wq_b — dead (softmax row-sums == 1)
    const float* wv_w    = (const float*)d_in[8];
    const float* wv_b    = (const float*)d_in[9];
    const float* wih     = (const float*)d_in[10];
    const float* whh     = (const float*)d_in[11];
    const float* bih     = (const float*)d_in[12];
    const float* bhh     = (const float*)d_in[13];

    char* ws = (char*)d_ws;
    size_t off = 0;
    auto alloc = [&](size_t bytes) -> char* {
        char* p = ws + off; off += (bytes + 255) & ~(size_t)255; return p;
    };
    unsigned short* imgB = (unsigned short*)alloc((size_t)cM * cIMG * 2);
    unsigned short* wlB  = (unsigned short*)alloc((size_t)cE * cIMG * 2);
    unsigned short* wvB  = (unsigned short*)alloc((size_t)cE * cE * 2);
    unsigned short* wihB = (unsigned short*)alloc((size_t)cH3 * cE * 2);
    unsigned short* whhB = (unsigned short*)alloc((size_t)cH3 * cE * 2);
    float*          fpre = (float*)alloc((size_t)cM * cE * 4);
    unsigned short* fB   = (unsigned short*)alloc((size_t)cM * cE * 2);
    unsigned short* f2B  = (unsigned short*)alloc((size_t)cM * cE * 2);
    unsigned short* giB  = (unsigned short*)alloc((size_t)cM * cH3 * 2);
    float*          hfin = (float*)alloc((size_t)cB * cE * 4);
    unsigned short* hb0  = (unsigned short*)alloc((size_t)cB * cE * 2);
    unsigned short* hb1  = (unsigned short*)alloc((size_t)cB * cE * 2);
    unsigned*       bar  = (unsigned*)alloc(8192 * 4);
    (void)ws_size;

    // bf16 conversions
    cvt_f32_bf16<<<2048, 256, 0, stream>>>(images, imgB, cM * cIMG / 4);
    cvt_f32_bf16<<<512, 256, 0, stream>>>(wl_w, wlB, cE * cIMG / 4);
    cvt_f32_bf16<<<256, 256, 0, stream>>>(wv_w, wvB, cE * cE / 4);
    cvt_f32_bf16<<<512, 256, 0, stream>>>(wih, wihB, cH3 * cE / 4);
    cvt_f32_bf16<<<512, 256, 0, stream>>>(whh, whhB, cH3 * cE / 4);

    // G1: fpre = images @ wl_w^T + wl_b            (9216x1024, K=2048)
    gemm_bt<0><<<72 * 8, 256, 0, stream>>>(imgB, wlB, wl_b, nullptr,
                                           fpre, nullptr, cM, cE, cIMG, 72);
    // f = l2norm(fpre) + oimages  (in-place f32 + bf16 shadow)
    l2norm_add<<<cM, 256, 0, stream>>>(fpre, oimages, fpre, fB);

    // G2: f2 = f @ wv_w^T + wv_b + f               (attn == v shortcut)
    gemm_bt<2><<<72 * 8, 256, 0, stream>>>(fB, wvB, wv_b, fpre,
                                           nullptr, f2B, cM, cE, cE, 72);
    // G3: gi = f2 @ gru_wih^T + bih, remapped to (t*256+b) row order
    gemm_bt<3><<<72 * 24, 256, 0, stream>>>(f2B, wihB, bih, nullptr,
                                            nullptr, giB, cM, cH3, cE, 72);

    zero_state<<<1024, 256, 0, stream>>>(hb0, bar);

    void* args[] = { (void*)&whhB, (void*)&giB, (void*)&bhh, (void*)&hb0,
                     (void*)&hb1, (void*)&hfin, (void*)&bar };
    hipLaunchCooperativeKernel((void*)gru_persist, dim3(NBLK), dim3(256),
                               args, 0, stream);

    final_norm<<<cB, 256, 0, stream>>>(hfin, (float*)d_out);
}

// Round 3
// 1015.717 us; speedup vs baseline: 1.4368x; 1.4368x over previous
//
#include <hip/hip_runtime.h>
#include <hip/hip_bf16.h>

#define DEVI __device__ __forceinline__

typedef short bf16x8 __attribute__((ext_vector_type(8)));
typedef float f32x4 __attribute__((ext_vector_type(4)));

#define NBLK_G 128   // persistent GRU blocks (2 groups of 64)

// ---- helpers -------------------------------------------------------------

DEVI unsigned short f2b(float f) {  // f32 -> bf16 bits, RNE
    union { float f; unsigned u; } x; x.f = f;
    unsigned r = x.u + 0x7fffu + ((x.u >> 16) & 1u);
    return (unsigned short)(r >> 16);
}

DEVI float b2f(unsigned short u) {
    union { unsigned u; float f; } x; x.u = ((unsigned)u) << 16; return x.f;
}

DEVI void gld_lds16(const void* g, void* l) {
    __builtin_amdgcn_global_load_lds(
        (const __attribute__((address_space(1))) void*)g,
        (__attribute__((address_space(3))) void*)l, 16, 0, 0);
}

// ---- f32 -> bf16 convert (vectorized, grid-stride) -----------------------

__global__ __launch_bounds__(256) void cvt_f32_bf16(
    const float* __restrict__ src, unsigned short* __restrict__ dst, int n4)
{
    int stride = gridDim.x * 256;
    for (int i = blockIdx.x * 256 + threadIdx.x; i < n4; i += stride) {
        float4 v = reinterpret_cast<const float4*>(src)[i];
        ushort4 o;
        o.x = f2b(v.x); o.y = f2b(v.y); o.z = f2b(v.z); o.w = f2b(v.w);
        reinterpret_cast<ushort4*>(dst)[i] = o;
    }
}

// ---- GEMM: C[M,N] = A[M,K] @ B[N,K]^T + bias[N] (+resid) -----------------
// tile 128x128, BK=32, 4 waves, double-buffered global_load_lds staging.
// EPI: 0 = f32 out, 2 = bf16 out + f32 residual, 3 = bf16 out remapped
//      row (b*36+t) -> (t*256+b)   [for step-contiguous gi]

template<int EPI>
__global__ __launch_bounds__(256) void gemm_bt(
    const unsigned short* __restrict__ A, const unsigned short* __restrict__ Bm,
    const float* __restrict__ bias, const float* resid,
    float* outF, unsigned short* outB,
    int Mn, int Nn, int K, int mtiles)
{
    __shared__ short lds[2][2][128 * 32];
    const int tid = threadIdx.x;
    const int lane = tid & 63, w = tid >> 6;
    const int bid = blockIdx.x;
    const int mt = bid % mtiles, nt = bid / mtiles;
    const int m0 = mt * 128, n0 = nt * 128;
    const int fr = lane & 15, kg = lane >> 4;
    const int wr = (w >> 1) * 64, wc = (w & 1) * 64;

    auto stage = [&](int buf, int k0) {
#pragma unroll
        for (int rnd = 0; rnd < 2; ++rnd) {
            int chunk = rnd * 256 + w * 64;      // wave-uniform
            int slot = chunk + lane;
            int row = slot >> 2, ks = slot & 3;
            gld_lds16(A + (size_t)(m0 + row) * K + k0 + ks * 8,
                      (void*)&lds[buf][0][chunk * 8]);
        }
#pragma unroll
        for (int rnd = 0; rnd < 2; ++rnd) {
            int chunk = rnd * 256 + w * 64;
            int slot = chunk + lane;
            int row = slot >> 2, ks = slot & 3;
            gld_lds16(Bm + (size_t)(n0 + row) * K + k0 + ks * 8,
                      (void*)&lds[buf][1][chunk * 8]);
        }
    };

    f32x4 acc[4][4] = {};

    stage(0, 0);
    __syncthreads();
    const int nk = K >> 5;
    for (int kt = 0; kt < nk; ++kt) {
        int buf = kt & 1;
        if (kt + 1 < nk) stage(buf ^ 1, (kt + 1) * 32);
        const short* As = lds[buf][0];
        const short* Bs = lds[buf][1];
        bf16x8 af[4], bfv[4];
#pragma unroll
        for (int m = 0; m < 4; ++m)
            af[m] = *(const bf16x8*)&As[(wr + m * 16 + fr) * 32 + kg * 8];
#pragma unroll
        for (int n = 0; n < 4; ++n)
            bfv[n] = *(const bf16x8*)&Bs[(wc + n * 16 + fr) * 32 + kg * 8];
#pragma unroll
        for (int m = 0; m < 4; ++m)
#pragma unroll
            for (int n = 0; n < 4; ++n)
                acc[m][n] = __builtin_amdgcn_mfma_f32_16x16x32_bf16(
                    af[m], bfv[n], acc[m][n], 0, 0, 0);
        __syncthreads();
    }

    // epilogue: D[row][col], col = lane&15, row = (lane>>4)*4 + reg
#pragma unroll
    for (int n = 0; n < 4; ++n) {
        int col = n0 + wc + n * 16 + fr;
        float bc = bias[col];
#pragma unroll
        for (int m = 0; m < 4; ++m) {
            f32x4 v = acc[m][n];
#pragma unroll
            for (int i = 0; i < 4; ++i) {
                int row = m0 + wr + m * 16 + kg * 4 + i;
                float val = v[i] + bc;
                if (EPI == 0) {
                    outF[(size_t)row * Nn + col] = val;
                } else if (EPI == 2) {
                    size_t idx = (size_t)row * Nn + col;
                    val += resid[idx];
                    outB[idx] = f2b(val);
                } else {  // EPI == 3: remap (b*36+t) -> (t*256+b)
                    int b = row / 36, t = row - b * 36;
                    outB[(size_t)(t * 256 + b) * Nn + col] = f2b(val);
                }
            }
        }
    }
}

// ---- l2norm over last dim (1024) + broadcast-add oimages -----------------

__global__ __launch_bounds__(256) void l2norm_add(
    const float* fin, const float* __restrict__ oimg,
    float* foutF, unsigned short* __restrict__ foutB)
{
    int row = blockIdx.x;          // 0..9215  (b*36+n)
    int b = row / 36;
    float4 v = reinterpret_cast<const float4*>(fin + (size_t)row * 1024)[threadIdx.x];
    float s = v.x * v.x + v.y * v.y + v.z * v.z + v.w * v.w;
#pragma unroll
    for (int o = 32; o; o >>= 1) s += __shfl_down(s, o, 64);
    __shared__ float ws4[4];
    int lane = threadIdx.x & 63, w = threadIdx.x >> 6;
    if (lane == 0) ws4[w] = s;
    __syncthreads();
    float tot = ws4[0] + ws4[1] + ws4[2] + ws4[3];
    float inv = 1.0f / (sqrtf(tot) + 1e-8f);
    float4 o4 = reinterpret_cast<const float4*>(oimg + (size_t)b * 1024)[threadIdx.x];
    float4 y;
    y.x = v.x * inv + o4.x; y.y = v.y * inv + o4.y;
    y.z = v.z * inv + o4.z; y.w = v.w * inv + o4.w;
    reinterpret_cast<float4*>(foutF + (size_t)row * 1024)[threadIdx.x] = y;
    ushort4 yb; yb.x = f2b(y.x); yb.y = f2b(y.y); yb.z = f2b(y.z); yb.w = f2b(y.w);
    reinterpret_cast<ushort4*>(foutB + (size_t)row * 1024)[threadIdx.x] = yb;
}

// ---- persistent GRU: all 36 steps in one cooperative kernel ---------------
// 128 blocks x 512 threads: block = (col-tile c in 0..63, batch-half p in 0..1).
// Block computes h[p*128 .. p*128+128, c*16 .. c*16+16] each step.
// whh slice (48x1024 bf16, 96 KB, XOR-swizzled) LDS-resident for all steps.
// h ping-pong crosses blocks ONLY via relaxed agent-scope atomics (L2-bypass,
// coherent at L3) -> NO cache invalidates needed anywhere. Barrier: one
// RELEASE fetch_add per block per step + RELAXED polling (no inv per poll —
// this was the round-2 catastrophe). Two independent 64-block groups.

__global__ __launch_bounds__(512, 2) void gru_persist(
    const unsigned short* __restrict__ whhB,   // (3072,1024) bf16
    const unsigned short* __restrict__ giB,    // (36*256, 3072) bf16, t-major
    const float* __restrict__ bhh,
    unsigned short* hA,                        // ping (256,1024) bf16
    unsigned short* hBb,                       // pong
    float* __restrict__ hfin,                  // (256,1024) f32 final
    unsigned* bar)
{
    __shared__ short whs[48 * 1024];           // 96 KB
    const int tid = threadIdx.x, lane = tid & 63, w = tid >> 6;  // w: 0..7
    const int bid = blockIdx.x;
    const int c = bid >> 1, p = bid & 1;
    const int e0 = c * 16;
    const int fr = lane & 15, kg = lane >> 4;
    const int szk = fr & 7;                    // chunk-XOR swizzle key

    // one-time whh slice load: 48 rows x 128 16B-chunks, pre-swizzled source
    for (int it = 0; it < 12; ++it) {
        int slot = it * 512 + tid;             // dest = wave-uniform + lane*16
        int j = slot >> 7, pc = slot & 127;
        int gc = pc ^ (j & 7);
        int grow = (j >> 4) * 1024 + e0 + (j & 15);
        gld_lds16(whhB + (size_t)grow * 1024 + gc * 8, (void*)&whs[slot * 8]);
    }
    __syncthreads();

    const int e = e0 + fr;
    const float bhr = bhh[e], bhz = bhh[1024 + e], bhn = bhh[2048 + e];
    float hreg[4] = {0.f, 0.f, 0.f, 0.f};
    int bb[4];
#pragma unroll
    for (int i = 0; i < 4; ++i) bb[i] = p * 128 + w * 16 + kg * 4 + i;
    const int arow = p * 128 + w * 16 + fr;    // this lane's A-row (batch)
    unsigned* cnt = &bar[p * 32];              // per-group counter, 128B apart

    unsigned short* hbuf[2] = { hA, hBb };

    for (int t = 0; t < 36; ++t) {
        const unsigned short* hc = hbuf[t & 1];
        unsigned short* hn = hbuf[(t + 1) & 1];

        // gi for this step (plain cached loads, read-only; issue early so the
        // ~L3 latency hides under the h-load + MFMA phase)
        const unsigned short* gbase = giB + (size_t)t * 256 * 3072 + e;
        unsigned short giu[4][3];
#pragma unroll
        for (int i = 0; i < 4; ++i) {
            const unsigned short* g = gbase + (size_t)bb[i] * 3072;
            giu[i][0] = g[0]; giu[i][1] = g[1024]; giu[i][2] = g[2048];
        }

        // h A-fragments: coherent (L2-bypassing) relaxed agent atomic loads
        unsigned long long* hq =
            (unsigned long long*)(hc + (size_t)arow * 1024 + kg * 8);
        bf16x8 av[32];
#pragma unroll
        for (int kt = 0; kt < 32; ++kt) {
            unsigned long long q0 = __hip_atomic_load(
                hq + kt * 8, __ATOMIC_RELAXED, __HIP_MEMORY_SCOPE_AGENT);
            unsigned long long q1 = __hip_atomic_load(
                hq + kt * 8 + 1, __ATOMIC_RELAXED, __HIP_MEMORY_SCOPE_AGENT);
            union { unsigned long long q[2]; bf16x8 v; } u;
            u.q[0] = q0; u.q[1] = q1;
            av[kt] = u.v;
        }

        f32x4 a0 = {}, a1 = {}, a2 = {};
#pragma unroll
        for (int kt = 0; kt < 32; ++kt) {
            const int pc0 = ((kt * 4 + kg) ^ szk) << 3;
            bf16x8 w0 = *(const bf16x8*)&whs[(0 * 16 + fr) * 1024 + pc0];
            a0 = __builtin_amdgcn_mfma_f32_16x16x32_bf16(av[kt], w0, a0, 0, 0, 0);
            bf16x8 w1 = *(const bf16x8*)&whs[(1 * 16 + fr) * 1024 + pc0];
            a1 = __builtin_amdgcn_mfma_f32_16x16x32_bf16(av[kt], w1, a1, 0, 0, 0);
            bf16x8 w2 = *(const bf16x8*)&whs[(2 * 16 + fr) * 1024 + pc0];
            a2 = __builtin_amdgcn_mfma_f32_16x16x32_bf16(av[kt], w2, a2, 0, 0, 0);
        }

        // gate math; h state stays in f32 registers
#pragma unroll
        for (int i = 0; i < 4; ++i) {
            float ir = b2f(giu[i][0]), iz = b2f(giu[i][1]), inn = b2f(giu[i][2]);
            float r = 1.f / (1.f + __expf(-(ir + a0[i] + bhr)));
            float z = 1.f / (1.f + __expf(-(iz + a1[i] + bhz)));
            float n = tanhf(inn + r * (a2[i] + bhn));
            hreg[i] = (1.f - z) * n + z * hreg[i];
        }

        if (t == 35) {
#pragma unroll
            for (int i = 0; i < 4; ++i)
                hfin[(size_t)bb[i] * 1024 + e] = hreg[i];
        } else {
            // write-through h shadow (coherent at L3)
#pragma unroll
            for (int i = 0; i < 4; ++i)
                __hip_atomic_store(&hn[(size_t)bb[i] * 1024 + e], f2b(hreg[i]),
                                   __ATOMIC_RELAXED, __HIP_MEMORY_SCOPE_AGENT);
            __syncthreads();   // all waves' stores vmcnt-retired before arrive
            if (tid == 0) {
                __hip_atomic_fetch_add(cnt, 1u, __ATOMIC_RELEASE,
                                       __HIP_MEMORY_SCOPE_AGENT);
                const unsigned target = 64u * (unsigned)(t + 1);
                int guard = 0;
                while (__hip_atomic_load(cnt, __ATOMIC_RELAXED,
                                         __HIP_MEMORY_SCOPE_AGENT) < target) {
                    __builtin_amdgcn_s_sleep(2);
                    if (++guard > (1 << 24)) break;
                }
            }
            __syncthreads();
        }
    }
}

__global__ __launch_bounds__(256) void zero_state(
    unsigned short* hb0, unsigned* bar)
{
    int i = blockIdx.x * 256 + threadIdx.x;    // grid 1024 -> 262144
    if (i < 256 * 1024) hb0[i] = 0;
    if (i < 8192) bar[i] = 0;
}

__global__ __launch_bounds__(256) void final_norm(
    const float* __restrict__ hf, float* __restrict__ out)
{
    int row = blockIdx.x;   // 0..255
    float4 v = reinterpret_cast<const float4*>(hf + (size_t)row * 1024)[threadIdx.x];
    float s = v.x * v.x + v.y * v.y + v.z * v.z + v.w * v.w;
#pragma unroll
    for (int o = 32; o; o >>= 1) s += __shfl_down(s, o, 64);
    __shared__ float ws4[4];
    int lane = threadIdx.x & 63, w = threadIdx.x >> 6;
    if (lane == 0) ws4[w] = s;
    __syncthreads();
    float tot = ws4[0] + ws4[1] + ws4[2] + ws4[3];
    float inv = 1.0f / (sqrtf(tot) + 1e-8f);
    float4 y; y.x = v.x * inv; y.y = v.y * inv; y.z = v.z * inv; y.w = v.w * inv;
    reinterpret_cast<float4*>(out + (size_t)row * 1024)[threadIdx.x] = y;
}

// ---- launch ---------------------------------------------------------------

extern "C" void kernel_launch(void* const* d_in, const int* in_sizes, int n_in,
                              void* d_out, int out_size, void* d_ws, size_t ws_size,
                              hipStream_t stream)
{
    constexpr int cB = 256, cN = 36, cIMG = 2048, cE = 1024, cH3 = 3072;
    constexpr int cM = cB * cN;  // 9216

    const float* images  = (const float*)d_in[0];
    const float* oimages = (const float*)d_in[1];
    const float* wl_w    = (const float*)d_in[2];
    const float* wl_b    = (const float*)d_in[3];
    // d_in[4..7]: wk_w, wk_b, wq_w, wq_b — dead (softmax row-sums == 1)
    const float* wv_w    = (const float*)d_in[8];
    const float* wv_b    = (const float*)d_in[9];
    const float* wih     = (const float*)d_in[10];
    const float* whh     = (const float*)d_in[11];
    const float* bih     = (const float*)d_in[12];
    const float* bhh     = (const float*)d_in[13];

    char* ws = (char*)d_ws;
    size_t off = 0;
    auto alloc = [&](size_t bytes) -> char* {
        char* p = ws + off; off += (bytes + 255) & ~(size_t)255; return p;
    };
    unsigned short* imgB = (unsigned short*)alloc((size_t)cM * cIMG * 2);
    unsigned short* wlB  = (unsigned short*)alloc((size_t)cE * cIMG * 2);
    unsigned short* wvB  = (unsigned short*)alloc((size_t)cE * cE * 2);
    unsigned short* wihB = (unsigned short*)alloc((size_t)cH3 * cE * 2);
    unsigned short* whhB = (unsigned short*)alloc((size_t)cH3 * cE * 2);
    float*          fpre = (float*)alloc((size_t)cM * cE * 4);
    unsigned short* fB   = (unsigned short*)alloc((size_t)cM * cE * 2);
    unsigned short* f2B  = (unsigned short*)alloc((size_t)cM * cE * 2);
    unsigned short* giB  = (unsigned short*)alloc((size_t)cM * cH3 * 2);
    float*          hfin = (float*)alloc((size_t)cB * cE * 4);
    unsigned short* hb0  = (unsigned short*)alloc((size_t)cB * cE * 2);
    unsigned short* hb1  = (unsigned short*)alloc((size_t)cB * cE * 2);
    unsigned*       bar  = (unsigned*)alloc(8192 * 4);
    (void)ws_size;

    // bf16 conversions
    cvt_f32_bf16<<<2048, 256, 0, stream>>>(images, imgB, cM * cIMG / 4);
    cvt_f32_bf16<<<512, 256, 0, stream>>>(wl_w, wlB, cE * cIMG / 4);
    cvt_f32_bf16<<<256, 256, 0, stream>>>(wv_w, wvB, cE * cE / 4);
    cvt_f32_bf16<<<512, 256, 0, stream>>>(wih, wihB, cH3 * cE / 4);
    cvt_f32_bf16<<<512, 256, 0, stream>>>(whh, whhB, cH3 * cE / 4);

    // G1: fpre = images @ wl_w^T + wl_b            (9216x1024, K=2048)
    gemm_bt<0><<<72 * 8, 256, 0, stream>>>(imgB, wlB, wl_b, nullptr,
                                           fpre, nullptr, cM, cE, cIMG, 72);
    // f = l2norm(fpre) + oimages  (in-place f32 + bf16 shadow)
    l2norm_add<<<cM, 256, 0, stream>>>(fpre, oimages, fpre, fB);

    // G2: f2 = f @ wv_w^T + wv_b + f               (attn == v shortcut)
    gemm_bt<2><<<72 * 8, 256, 0, stream>>>(fB, wvB, wv_b, fpre,
                                           nullptr, f2B, cM, cE, cE, 72);
    // G3: gi = f2 @ gru_wih^T + bih, remapped to (t*256+b) row order
    gemm_bt<3><<<72 * 24, 256, 0, stream>>>(f2B, wihB, bih, nullptr,
                                            nullptr, giB, cM, cH3, cE, 72);

    zero_state<<<1024, 256, 0, stream>>>(hb0, bar);

    void* args[] = { (void*)&whhB, (void*)&giB, (void*)&bhh, (void*)&hb0,
                     (void*)&hb1, (void*)&hfin, (void*)&bar };
    hipLaunchCooperativeKernel((void*)gru_persist, dim3(NBLK_G), dim3(512),
                               args, 0, stream);

    final_norm<<<cB, 256, 0, stream>>>(hfin, (float*)d_out);
}

// Round 4
// 774.939 us; speedup vs baseline: 1.8832x; 1.3107x over previous
//
#include <hip/hip_runtime.h>
#include <hip/hip_bf16.h>

#define DEVI __device__ __forceinline__

typedef short bf16x8 __attribute__((ext_vector_type(8)));
typedef float f32x4 __attribute__((ext_vector_type(4)));

#define NBLK_G 128   // persistent GRU blocks (2 groups of 64)

// ---- helpers -------------------------------------------------------------

DEVI unsigned short f2b(float f) {  // f32 -> bf16 bits, RNE
    union { float f; unsigned u; } x; x.f = f;
    unsigned r = x.u + 0x7fffu + ((x.u >> 16) & 1u);
    return (unsigned short)(r >> 16);
}

DEVI float b2f(unsigned short u) {
    union { unsigned u; float f; } x; x.u = ((unsigned)u) << 16; return x.f;
}

DEVI void gld_lds16(const void* g, void* l) {
    __builtin_amdgcn_global_load_lds(
        (const __attribute__((address_space(1))) void*)g,
        (__attribute__((address_space(3))) void*)l, 16, 0, 0);
}

// ---- f32 -> bf16 convert (vectorized, grid-stride) -----------------------

__global__ __launch_bounds__(256) void cvt_f32_bf16(
    const float* __restrict__ src, unsigned short* __restrict__ dst, int n4)
{
    int stride = gridDim.x * 256;
    for (int i = blockIdx.x * 256 + threadIdx.x; i < n4; i += stride) {
        float4 v = reinterpret_cast<const float4*>(src)[i];
        ushort4 o;
        o.x = f2b(v.x); o.y = f2b(v.y); o.z = f2b(v.z); o.w = f2b(v.w);
        reinterpret_cast<ushort4*>(dst)[i] = o;
    }
}

// ---- GEMM: C[M,N] = A[M,K] @ B[N,K]^T + bias[N] (+resid) -----------------
// tile 128x128, BK=32, 4 waves, double-buffered global_load_lds staging.
// EPI: 0 = f32 out, 2 = bf16 out + f32 residual, 3 = bf16 out remapped
//      row (b*36+t) -> (t*256+b)   [for step-contiguous gi]

template<int EPI>
__global__ __launch_bounds__(256) void gemm_bt(
    const unsigned short* __restrict__ A, const unsigned short* __restrict__ Bm,
    const float* __restrict__ bias, const float* resid,
    float* outF, unsigned short* outB,
    int Mn, int Nn, int K, int mtiles)
{
    __shared__ short lds[2][2][128 * 32];
    const int tid = threadIdx.x;
    const int lane = tid & 63, w = tid >> 6;
    const int bid = blockIdx.x;
    const int mt = bid % mtiles, nt = bid / mtiles;
    const int m0 = mt * 128, n0 = nt * 128;
    const int fr = lane & 15, kg = lane >> 4;
    const int wr = (w >> 1) * 64, wc = (w & 1) * 64;

    auto stage = [&](int buf, int k0) {
#pragma unroll
        for (int rnd = 0; rnd < 2; ++rnd) {
            int chunk = rnd * 256 + w * 64;      // wave-uniform
            int slot = chunk + lane;
            int row = slot >> 2, ks = slot & 3;
            gld_lds16(A + (size_t)(m0 + row) * K + k0 + ks * 8,
                      (void*)&lds[buf][0][chunk * 8]);
        }
#pragma unroll
        for (int rnd = 0; rnd < 2; ++rnd) {
            int chunk = rnd * 256 + w * 64;
            int slot = chunk + lane;
            int row = slot >> 2, ks = slot & 3;
            gld_lds16(Bm + (size_t)(n0 + row) * K + k0 + ks * 8,
                      (void*)&lds[buf][1][chunk * 8]);
        }
    };

    f32x4 acc[4][4] = {};

    stage(0, 0);
    __syncthreads();
    const int nk = K >> 5;
    for (int kt = 0; kt < nk; ++kt) {
        int buf = kt & 1;
        if (kt + 1 < nk) stage(buf ^ 1, (kt + 1) * 32);
        const short* As = lds[buf][0];
        const short* Bs = lds[buf][1];
        bf16x8 af[4], bfv[4];
#pragma unroll
        for (int m = 0; m < 4; ++m)
            af[m] = *(const bf16x8*)&As[(wr + m * 16 + fr) * 32 + kg * 8];
#pragma unroll
        for (int n = 0; n < 4; ++n)
            bfv[n] = *(const bf16x8*)&Bs[(wc + n * 16 + fr) * 32 + kg * 8];
#pragma unroll
        for (int m = 0; m < 4; ++m)
#pragma unroll
            for (int n = 0; n < 4; ++n)
                acc[m][n] = __builtin_amdgcn_mfma_f32_16x16x32_bf16(
                    af[m], bfv[n], acc[m][n], 0, 0, 0);
        __syncthreads();
    }

    // epilogue: D[row][col], col = lane&15, row = (lane>>4)*4 + reg
#pragma unroll
    for (int n = 0; n < 4; ++n) {
        int col = n0 + wc + n * 16 + fr;
        float bc = bias[col];
#pragma unroll
        for (int m = 0; m < 4; ++m) {
            f32x4 v = acc[m][n];
#pragma unroll
            for (int i = 0; i < 4; ++i) {
                int row = m0 + wr + m * 16 + kg * 4 + i;
                float val = v[i] + bc;
                if (EPI == 0) {
                    outF[(size_t)row * Nn + col] = val;
                } else if (EPI == 2) {
                    size_t idx = (size_t)row * Nn + col;
                    val += resid[idx];
                    outB[idx] = f2b(val);
                } else {  // EPI == 3: remap (b*36+t) -> (t*256+b)
                    int b = row / 36, t = row - b * 36;
                    outB[(size_t)(t * 256 + b) * Nn + col] = f2b(val);
                }
            }
        }
    }
}

// ---- l2norm over last dim (1024) + broadcast-add oimages -----------------

__global__ __launch_bounds__(256) void l2norm_add(
    const float* fin, const float* __restrict__ oimg,
    float* foutF, unsigned short* __restrict__ foutB)
{
    int row = blockIdx.x;          // 0..9215  (b*36+n)
    int b = row / 36;
    float4 v = reinterpret_cast<const float4*>(fin + (size_t)row * 1024)[threadIdx.x];
    float s = v.x * v.x + v.y * v.y + v.z * v.z + v.w * v.w;
#pragma unroll
    for (int o = 32; o; o >>= 1) s += __shfl_down(s, o, 64);
    __shared__ float ws4[4];
    int lane = threadIdx.x & 63, w = threadIdx.x >> 6;
    if (lane == 0) ws4[w] = s;
    __syncthreads();
    float tot = ws4[0] + ws4[1] + ws4[2] + ws4[3];
    float inv = 1.0f / (sqrtf(tot) + 1e-8f);
    float4 o4 = reinterpret_cast<const float4*>(oimg + (size_t)b * 1024)[threadIdx.x];
    float4 y;
    y.x = v.x * inv + o4.x; y.y = v.y * inv + o4.y;
    y.z = v.z * inv + o4.z; y.w = v.w * inv + o4.w;
    reinterpret_cast<float4*>(foutF + (size_t)row * 1024)[threadIdx.x] = y;
    ushort4 yb; yb.x = f2b(y.x); yb.y = f2b(y.y); yb.z = f2b(y.z); yb.w = f2b(y.w);
    reinterpret_cast<ushort4*>(foutB + (size_t)row * 1024)[threadIdx.x] = yb;
}

// ---- persistent GRU: all 36 steps in one cooperative kernel ---------------
// 128 blocks x 512 threads: block = (col-tile c in 0..63, batch-half p in 0..1).
// whh slice (48x1024 bf16, 96 KB, XOR-swizzled) LDS-resident for all steps.
//
// Sync/data split (the round-2/3 lesson):
//   DATA:  plain cached vector loads/stores (coalesced, L2-served).
//   SYNC:  per step, per block: one RELEASE fetch_add (its buffer_wbl2
//          publishes the XCD's dirty h-lines to the Infinity Cache),
//          RELAXED polling (no cache maintenance per poll), then ONE
//          acquire fence (single buffer_inv: L1+L2 invalidate) before
//          re-reading h. Everything cached in L2 is either read-only or
//          read-once per step, so the once-per-step invalidate is cheap.

__global__ __launch_bounds__(512, 2) void gru_persist(
    const unsigned short* __restrict__ whhB,   // (3072,1024) bf16
    const unsigned short* __restrict__ giB,    // (36*256, 3072) bf16, t-major
    const float* __restrict__ bhh,
    unsigned short* hA,                        // ping (256,1024) bf16
    unsigned short* hBb,                       // pong
    float* __restrict__ hfin,                  // (256,1024) f32 final
    unsigned* bar)
{
    __shared__ short whs[48 * 1024];           // 96 KB
    const int tid = threadIdx.x, lane = tid & 63, w = tid >> 6;  // w: 0..7
    const int bid = blockIdx.x;
    const int c = bid >> 1, p = bid & 1;
    const int e0 = c * 16;
    const int fr = lane & 15, kg = lane >> 4;
    const int szk = fr & 7;                    // chunk-XOR swizzle key

    // one-time whh slice load: 48 rows x 128 16B-chunks, pre-swizzled source
    for (int it = 0; it < 12; ++it) {
        int slot = it * 512 + tid;             // dest = wave-uniform + lane*16
        int j = slot >> 7, pc = slot & 127;
        int gc = pc ^ (j & 7);
        int grow = (j >> 4) * 1024 + e0 + (j & 15);
        gld_lds16(whhB + (size_t)grow * 1024 + gc * 8, (void*)&whs[slot * 8]);
    }
    __syncthreads();

    const int e = e0 + fr;
    const float bhr = bhh[e], bhz = bhh[1024 + e], bhn = bhh[2048 + e];
    float hreg[4] = {0.f, 0.f, 0.f, 0.f};
    int bb[4];
#pragma unroll
    for (int i = 0; i < 4; ++i) bb[i] = p * 128 + w * 16 + kg * 4 + i;
    const int arow = p * 128 + w * 16 + fr;    // this lane's A-row (batch)
    unsigned* cnt = &bar[p * 32];              // per-group counter, 128B apart

    unsigned short* hbuf[2] = { hA, hBb };

    for (int t = 0; t < 36; ++t) {
        const unsigned short* hc = hbuf[t & 1];
        unsigned short* hn = hbuf[(t + 1) & 1];

        // gi for this step (read-once, HBM/IC; issue early so latency hides
        // under the h-load + MFMA phase)
        const unsigned short* gbase = giB + (size_t)t * 256 * 3072 + e;
        unsigned short giu[4][3];
#pragma unroll
        for (int i = 0; i < 4; ++i) {
            const unsigned short* g = gbase + (size_t)bb[i] * 3072;
            giu[i][0] = g[0]; giu[i][1] = g[1024]; giu[i][2] = g[2048];
        }

        // h A-fragments: PLAIN cached vector loads (dwordx4, coalesced;
        // 64 blocks/group share the same 256 KB half -> L2 hits)
        const unsigned short* hrow = hc + (size_t)arow * 1024 + kg * 8;
        f32x4 a0 = {}, a1 = {}, a2 = {};
#pragma unroll
        for (int kt = 0; kt < 32; ++kt) {
            bf16x8 av = *(const bf16x8*)(hrow + kt * 32);
            const int pc0 = ((kt * 4 + kg) ^ szk) << 3;
            bf16x8 w0 = *(const bf16x8*)&whs[(0 * 16 + fr) * 1024 + pc0];
            a0 = __builtin_amdgcn_mfma_f32_16x16x32_bf16(av, w0, a0, 0, 0, 0);
            bf16x8 w1 = *(const bf16x8*)&whs[(1 * 16 + fr) * 1024 + pc0];
            a1 = __builtin_amdgcn_mfma_f32_16x16x32_bf16(av, w1, a1, 0, 0, 0);
            bf16x8 w2 = *(const bf16x8*)&whs[(2 * 16 + fr) * 1024 + pc0];
            a2 = __builtin_amdgcn_mfma_f32_16x16x32_bf16(av, w2, a2, 0, 0, 0);
        }

        // gate math; h state stays in f32 registers
#pragma unroll
        for (int i = 0; i < 4; ++i) {
            float ir = b2f(giu[i][0]), iz = b2f(giu[i][1]), inn = b2f(giu[i][2]);
            float r = 1.f / (1.f + __expf(-(ir + a0[i] + bhr)));
            float z = 1.f / (1.f + __expf(-(iz + a1[i] + bhz)));
            float n = tanhf(inn + r * (a2[i] + bhn));
            hreg[i] = (1.f - z) * n + z * hreg[i];
        }

        if (t == 35) {
#pragma unroll
            for (int i = 0; i < 4; ++i)
                hfin[(size_t)bb[i] * 1024 + e] = hreg[i];
        } else {
            // plain cached stores of the bf16 shadow
#pragma unroll
            for (int i = 0; i < 4; ++i)
                hn[(size_t)bb[i] * 1024 + e] = f2b(hreg[i]);
            __syncthreads();   // every wave drains vmcnt before s_barrier ->
                               // all h stores are in L2 when tid0 proceeds
            if (tid == 0) {
                // release: waits tid0 vmcnt + buffer_wbl2 (publishes the
                // XCD's dirty lines, incl. other waves'/blocks' h stores)
                __hip_atomic_fetch_add(cnt, 1u, __ATOMIC_RELEASE,
                                       __HIP_MEMORY_SCOPE_AGENT);
                const unsigned target = 64u * (unsigned)(t + 1);
                int guard = 0;
                while (__hip_atomic_load(cnt, __ATOMIC_RELAXED,
                                         __HIP_MEMORY_SCOPE_AGENT) < target) {
                    __builtin_amdgcn_s_sleep(1);
                    if (++guard > (1 << 24)) break;
                }
                // ONE acquire fence per block per step: L1+L2 invalidate,
                // next h loads refill fresh from the IC coherence point
                __builtin_amdgcn_fence(__ATOMIC_ACQUIRE, "agent");
            }
            __syncthreads();
        }
    }
}

__global__ __launch_bounds__(256) void zero_state(
    unsigned short* hb0, unsigned* bar)
{
    int i = blockIdx.x * 256 + threadIdx.x;    // grid 1024 -> 262144
    if (i < 256 * 1024) hb0[i] = 0;
    if (i < 8192) bar[i] = 0;
}

__global__ __launch_bounds__(256) void final_norm(
    const float* __restrict__ hf, float* __restrict__ out)
{
    int row = blockIdx.x;   // 0..255
    float4 v = reinterpret_cast<const float4*>(hf + (size_t)row * 1024)[threadIdx.x];
    float s = v.x * v.x + v.y * v.y + v.z * v.z + v.w * v.w;
#pragma unroll
    for (int o = 32; o; o >>= 1) s += __shfl_down(s, o, 64);
    __shared__ float ws4[4];
    int lane = threadIdx.x & 63, w = threadIdx.x >> 6;
    if (lane == 0) ws4[w] = s;
    __syncthreads();
    float tot = ws4[0] + ws4[1] + ws4[2] + ws4[3];
    float inv = 1.0f / (sqrtf(tot) + 1e-8f);
    float4 y; y.x = v.x * inv; y.y = v.y * inv; y.z = v.z * inv; y.w = v.w * inv;
    reinterpret_cast<float4*>(out + (size_t)row * 1024)[threadIdx.x] = y;
}

// ---- launch ---------------------------------------------------------------

extern "C" void kernel_launch(void* const* d_in, const int* in_sizes, int n_in,
                              void* d_out, int out_size, void* d_ws, size_t ws_size,
                              hipStream_t stream)
{
    constexpr int cB = 256, cN = 36, cIMG = 2048, cE = 1024, cH3 = 3072;
    constexpr int cM = cB * cN;  // 9216

    const float* images  = (const float*)d_in[0];
    const float* oimages = (const float*)d_in[1];
    const float* wl_w    = (const float*)d_in[2];
    const float* wl_b    = (const float*)d_in[3];
    // d_in[4..7]: wk_w, wk_b, wq_w, wq_b — dead (softmax row-sums == 1)
    const float* wv_w    = (const float*)d_in[8];
    const float* wv_b    = (const float*)d_in[9];
    const float* wih     = (const float*)d_in[10];
    const float* whh     = (const float*)d_in[11];
    const float* bih     = (const float*)d_in[12];
    const float* bhh     = (const float*)d_in[13];

    char* ws = (char*)d_ws;
    size_t off = 0;
    auto alloc = [&](size_t bytes) -> char* {
        char* p = ws + off; off += (bytes + 255) & ~(size_t)255; return p;
    };
    unsigned short* imgB = (unsigned short*)alloc((size_t)cM * cIMG * 2);
    unsigned short* wlB  = (unsigned short*)alloc((size_t)cE * cIMG * 2);
    unsigned short* wvB  = (unsigned short*)alloc((size_t)cE * cE * 2);
    unsigned short* wihB = (unsigned short*)alloc((size_t)cH3 * cE * 2);
    unsigned short* whhB = (unsigned short*)alloc((size_t)cH3 * cE * 2);
    float*          fpre = (float*)alloc((size_t)cM * cE * 4);
    unsigned short* fB   = (unsigned short*)alloc((size_t)cM * cE * 2);
    unsigned short* f2B  = (unsigned short*)alloc((size_t)cM * cE * 2);
    unsigned short* giB  = (unsigned short*)alloc((size_t)cM * cH3 * 2);
    float*          hfin = (float*)alloc((size_t)cB * cE * 4);
    unsigned short* hb0  = (unsigned short*)alloc((size_t)cB * cE * 2);
    unsigned short* hb1  = (unsigned short*)alloc((size_t)cB * cE * 2);
    unsigned*       bar  = (unsigned*)alloc(8192 * 4);
    (void)ws_size;

    // bf16 conversions
    cvt_f32_bf16<<<2048, 256, 0, stream>>>(images, imgB, cM * cIMG / 4);
    cvt_f32_bf16<<<512, 256, 0, stream>>>(wl_w, wlB, cE * cIMG / 4);
    cvt_f32_bf16<<<256, 256, 0, stream>>>(wv_w, wvB, cE * cE / 4);
    cvt_f32_bf16<<<512, 256, 0, stream>>>(wih, wihB, cH3 * cE / 4);
    cvt_f32_bf16<<<512, 256, 0, stream>>>(whh, whhB, cH3 * cE / 4);

    // G1: fpre = images @ wl_w^T + wl_b            (9216x1024, K=2048)
    gemm_bt<0><<<72 * 8, 256, 0, stream>>>(imgB, wlB, wl_b, nullptr,
                                           fpre, nullptr, cM, cE, cIMG, 72);
    // f = l2norm(fpre) + oimages  (in-place f32 + bf16 shadow)
    l2norm_add<<<cM, 256, 0, stream>>>(fpre, oimages, fpre, fB);

    // G2: f2 = f @ wv_w^T + wv_b + f               (attn == v shortcut)
    gemm_bt<2><<<72 * 8, 256, 0, stream>>>(fB, wvB, wv_b, fpre,
                                           nullptr, f2B, cM, cE, cE, 72);
    // G3: gi = f2 @ gru_wih^T + bih, remapped to (t*256+b) row order
    gemm_bt<3><<<72 * 24, 256, 0, stream>>>(f2B, wihB, bih, nullptr,
                                            nullptr, giB, cM, cH3, cE, 72);

    zero_state<<<1024, 256, 0, stream>>>(hb0, bar);

    void* args[] = { (void*)&whhB, (void*)&giB, (void*)&bhh, (void*)&hb0,
                     (void*)&hb1, (void*)&hfin, (void*)&bar };
    hipLaunchCooperativeKernel((void*)gru_persist, dim3(NBLK_G), dim3(512),
                               args, 0, stream);

    final_norm<<<cB, 256, 0, stream>>>(hfin, (float*)d_out);
}